// Round 1
// baseline (678.347 us; speedup 1.0000x reference)
//
#include <hip/hip_runtime.h>
#include <stdint.h>

typedef unsigned short u16;
typedef __attribute__((ext_vector_type(4))) u16 u16x4;
typedef __attribute__((ext_vector_type(8))) u16 u16x8;
typedef __attribute__((ext_vector_type(8))) __bf16 bf16x8;
typedef __attribute__((ext_vector_type(4))) float f32x4;

#define D_MODEL 2048
#define N_HEADS 16
#define HEAD_DIM 128
#define BATCH 2
#define SEQ 2048
#define M_TOT (BATCH*SEQ)          // 4096
#define N_QKV (3*D_MODEL)          // 6144

__device__ __forceinline__ u16 f2b(float f) {
  union { float f; uint32_t u; } c; c.f = f;
  uint32_t u = c.u;
  uint32_t r = (u + 0x7fffu + ((u >> 16) & 1u)) >> 16;
  return (u16)r;
}

__device__ __forceinline__ void gl_lds16(const u16* g, u16* l) {
  __builtin_amdgcn_global_load_lds(
      (const __attribute__((address_space(1))) uint32_t*)g,
      (__attribute__((address_space(3))) uint32_t*)l, 16, 0, 0);
}

// ---------------- prep kernels ----------------

__global__ void cast_x_kernel(const float* __restrict__ x, u16* __restrict__ xb, int n) {
  int i = (blockIdx.x * blockDim.x + threadIdx.x) * 4;
  if (i >= n) return;
  f32x4 v = *(const f32x4*)(x + i);
  u16x4 o;
  o[0] = f2b(v[0]); o[1] = f2b(v[1]); o[2] = f2b(v[2]); o[3] = f2b(v[3]);
  *(u16x4*)(xb + i) = o;
}

// Wq/Wk/Wv [H][2048][128] f32  ->  Wt [6144][2048] bf16, row n=(qkv*2048+h*128+d), K-major
__global__ void trans_wqkv_kernel(const float* __restrict__ Wq, const float* __restrict__ Wk,
                                  const float* __restrict__ Wv, u16* __restrict__ Wt) {
  __shared__ u16 Tl[128][72];
  const int hh = blockIdx.y;           // 0..47 = qkv*16+h
  const int qkv = hh >> 4, h = hh & 15;
  const float* src = (qkv == 0 ? Wq : qkv == 1 ? Wk : Wv) + (size_t)h * 2048 * 128;
  const int k0 = blockIdx.x * 64;
  const int tid = threadIdx.x;
  for (int it = 0; it < 32; ++it) {
    int idx = it * 256 + tid;
    int k = idx >> 7, d = idx & 127;
    Tl[d][k] = f2b(src[(size_t)(k0 + k) * 128 + d]);
  }
  __syncthreads();
  for (int it = 0; it < 32; ++it) {
    int idx = it * 256 + tid;
    int d = idx >> 6, kk = idx & 63;
    Wt[(size_t)(hh * 128 + d) * 2048 + k0 + kk] = Tl[d][kk];
  }
}

// Wo [2048][2048] f32 -> Wot [2048][2048] bf16 (transposed, K-major)
__global__ void trans_wo_kernel(const float* __restrict__ Wo, u16* __restrict__ Wot) {
  __shared__ u16 Tl[128][72];
  const int k0 = blockIdx.x * 64;     // 32 tiles
  const int n0 = blockIdx.y * 128;    // 16 tiles
  const int tid = threadIdx.x;
  for (int it = 0; it < 32; ++it) {
    int idx = it * 256 + tid;
    int k = idx >> 7, n = idx & 127;
    Tl[n][k] = f2b(Wo[(size_t)(k0 + k) * 2048 + n0 + n]);
  }
  __syncthreads();
  for (int it = 0; it < 32; ++it) {
    int idx = it * 256 + tid;
    int d = idx >> 6, kk = idx & 63;
    Wot[(size_t)(n0 + d) * 2048 + k0 + kk] = Tl[d][kk];
  }
}

// ---------------- GEMM (128x128 tile, BK=32, 4 waves, m97 structure) ----------------
// A [M][2048] bf16 row-major; B [N][2048] bf16 K-major (i.e. B[n][k]).
// EPI 0: scatter to q/k/v [B,H,T,D] bf16 + bias.  EPI 1: f32 out + bo.
template <int EPI>
__global__ __launch_bounds__(256) void gemm_kernel(
    const u16* __restrict__ A, const u16* __restrict__ B,
    u16* __restrict__ qo, u16* __restrict__ ko, u16* __restrict__ vo,
    const float* __restrict__ bq, const float* __restrict__ bk, const float* __restrict__ bv,
    float* __restrict__ outf, const float* __restrict__ bo) {
  __shared__ u16 As[128 * 32];
  __shared__ u16 Bs[128 * 32];
  const int tid = threadIdx.x;
  const int lane = tid & 63, wv = tid >> 6;
  const int m0 = blockIdx.y * 128, n0 = blockIdx.x * 128;
  const int wm = (wv >> 1) * 64, wn = (wv & 1) * 64;
  const int lr = lane & 15, lk = (lane >> 4) * 8;

  f32x4 zero = {0.f, 0.f, 0.f, 0.f};
  f32x4 acc[4][4];
#pragma unroll
  for (int i = 0; i < 4; ++i)
#pragma unroll
    for (int j = 0; j < 4; ++j) acc[i][j] = zero;

  const int e0 = tid * 8;            // element offset of this thread's 16B slot
  const int row0 = e0 >> 5;          // 32 elems per LDS row
  const int col0 = e0 & 31;
  const u16* Ag = A + (size_t)(m0 + row0) * 2048 + col0;
  const u16* Bg = B + (size_t)(n0 + row0) * 2048 + col0;

  for (int kt = 0; kt < 2048; kt += 32) {
    gl_lds16(Ag + kt, As + e0);
    gl_lds16(Ag + kt + (size_t)64 * 2048, As + e0 + 64 * 32);
    gl_lds16(Bg + kt, Bs + e0);
    gl_lds16(Bg + kt + (size_t)64 * 2048, Bs + e0 + 64 * 32);
    __syncthreads();
    bf16x8 af[4], bfm[4];
#pragma unroll
    for (int i = 0; i < 4; ++i) af[i] = *(const bf16x8*)(As + (wm + i * 16 + lr) * 32 + lk);
#pragma unroll
    for (int j = 0; j < 4; ++j) bfm[j] = *(const bf16x8*)(Bs + (wn + j * 16 + lr) * 32 + lk);
#pragma unroll
    for (int i = 0; i < 4; ++i)
#pragma unroll
      for (int j = 0; j < 4; ++j)
        acc[i][j] = __builtin_amdgcn_mfma_f32_16x16x32_bf16(af[i], bfm[j], acc[i][j], 0, 0, 0);
    __syncthreads();
  }

  const int rbase = (lane >> 4) * 4;
  if (EPI == 0) {
    const int qkv = n0 >> 11, h = (n0 >> 7) & 15;
    const float* bias = (qkv == 0) ? bq : (qkv == 1) ? bk : bv;
    u16* dst = (qkv == 0) ? qo : (qkv == 1) ? ko : vo;
#pragma unroll
    for (int i = 0; i < 4; ++i)
#pragma unroll
      for (int j = 0; j < 4; ++j)
#pragma unroll
        for (int r = 0; r < 4; ++r) {
          int gm = m0 + wm + i * 16 + rbase + r;
          int d = wn + j * 16 + (lane & 15);
          float val = acc[i][j][r] + bias[h * 128 + d];
          int b = gm >> 11, t = gm & 2047;
          dst[((size_t)(b * 16 + h) * 2048 + t) * 128 + d] = f2b(val);
        }
  } else {
#pragma unroll
    for (int i = 0; i < 4; ++i)
#pragma unroll
      for (int j = 0; j < 4; ++j)
#pragma unroll
        for (int r = 0; r < 4; ++r) {
          int gm = m0 + wm + i * 16 + rbase + r;
          int gn = n0 + wn + j * 16 + (lane & 15);
          outf[(size_t)gm * 2048 + gn] = acc[i][j][r] + bo[gn];
        }
  }
}

// ---------------- flash attention (causal) ----------------
// grid (T/64, H, B), 256 threads. Each wave owns 16 q-rows; KV tile = 64.
__global__ __launch_bounds__(256) void attn_kernel(
    const u16* __restrict__ qg, const u16* __restrict__ kg, const u16* __restrict__ vg,
    u16* __restrict__ y) {
  __shared__ u16 Kl[64 * 128];
  __shared__ u16 Vt[128 * 64];     // Vt[d][s]
  __shared__ u16 Pl[4][16 * 64];   // per-wave P
  const int tid = threadIdx.x, lane = tid & 63, w = tid >> 6;
  const int b = blockIdx.z, h = blockIdx.y;
  const int q0 = blockIdx.x * 64;
  const int lr = lane & 15, lk = (lane >> 4) * 8;
  const size_t bh = ((size_t)b * 16 + h) * 2048;
  const u16* Qp = qg + bh * 128;
  const u16* Kp = kg + bh * 128;
  const u16* Vp = vg + bh * 128;

  const int qw = q0 + w * 16;
  bf16x8 qf[4];
#pragma unroll
  for (int i = 0; i < 4; ++i)
    qf[i] = *(const bf16x8*)(Qp + (size_t)(qw + lr) * 128 + i * 32 + lk);

  f32x4 zero = {0.f, 0.f, 0.f, 0.f};
  f32x4 o[8];
#pragma unroll
  for (int f = 0; f < 8; ++f) o[f] = zero;
  float mrow[4], lrow[4];
#pragma unroll
  for (int r = 0; r < 4; ++r) { mrow[r] = -1e30f; lrow[r] = 0.f; }

  const float scale = 0.08838834764831845f;  // 1/sqrt(128)
  const int rq = qw + (lane >> 4) * 4;       // + r = global q row (output layout)
  const int e0 = tid * 8;

  for (int s0 = 0; s0 <= q0 + 63; s0 += 64) {
    // stage K (row-major) via global_load_lds
#pragma unroll
    for (int c = 0; c < 4; ++c) {
      int e = e0 + c * 2048;
      int srow = e >> 7, scol = e & 127;
      gl_lds16(Kp + (size_t)(s0 + srow) * 128 + scol, Kl + e);
    }
    // stage V transposed (manual)
#pragma unroll
    for (int c = 0; c < 4; ++c) {
      int e = e0 + c * 2048;
      int srow = e >> 7, scol = e & 127;
      u16x8 vv = *(const u16x8*)(Vp + (size_t)(s0 + srow) * 128 + scol);
#pragma unroll
      for (int ee = 0; ee < 8; ++ee) Vt[(scol + ee) * 64 + srow] = vv[ee];
    }
    __syncthreads();

    // QK^T: 16 q-rows x 64 s-cols per wave
    f32x4 sf[4];
#pragma unroll
    for (int sj = 0; sj < 4; ++sj) {
      f32x4 s = zero;
#pragma unroll
      for (int i = 0; i < 4; ++i) {
        bf16x8 kf = *(const bf16x8*)(Kl + (sj * 16 + lr) * 128 + i * 32 + lk);
        s = __builtin_amdgcn_mfma_f32_16x16x32_bf16(qf[i], kf, s, 0, 0, 0);
      }
      sf[sj] = s;
    }

    float sfac[4];
#pragma unroll
    for (int r = 0; r < 4; ++r) {
      float pm = -1e30f;
#pragma unroll
      for (int sj = 0; sj < 4; ++sj) {
        float val = sf[sj][r] * scale;
        int sg = s0 + sj * 16 + lr;
        if (sg > rq + r) val = -1e30f;
        sf[sj][r] = val;
        pm = fmaxf(pm, val);
      }
      pm = fmaxf(pm, __shfl_xor(pm, 1));
      pm = fmaxf(pm, __shfl_xor(pm, 2));
      pm = fmaxf(pm, __shfl_xor(pm, 4));
      pm = fmaxf(pm, __shfl_xor(pm, 8));
      float mnew = fmaxf(mrow[r], pm);
      sfac[r] = __expf(mrow[r] - mnew);
      mrow[r] = mnew;
      float ps = 0.f;
#pragma unroll
      for (int sj = 0; sj < 4; ++sj) {
        float p = __expf(sf[sj][r] - mnew);
        sf[sj][r] = p;
        ps += p;
      }
      ps += __shfl_xor(ps, 1);
      ps += __shfl_xor(ps, 2);
      ps += __shfl_xor(ps, 4);
      ps += __shfl_xor(ps, 8);
      lrow[r] = lrow[r] * sfac[r] + ps;
#pragma unroll
      for (int sj = 0; sj < 4; ++sj)
        Pl[w][((lane >> 4) * 4 + r) * 64 + sj * 16 + lr] = f2b(sf[sj][r]);
    }
#pragma unroll
    for (int f = 0; f < 8; ++f)
#pragma unroll
      for (int r = 0; r < 4; ++r) o[f][r] *= sfac[r];

    // PV: O[16][128] += P[16][64] * V[64][128]
#pragma unroll
    for (int st = 0; st < 2; ++st) {
      bf16x8 pf = *(const bf16x8*)(&Pl[w][lr * 64 + st * 32 + lk]);
#pragma unroll
      for (int f = 0; f < 8; ++f) {
        bf16x8 vf = *(const bf16x8*)(Vt + (f * 16 + lr) * 64 + st * 32 + lk);
        o[f] = __builtin_amdgcn_mfma_f32_16x16x32_bf16(pf, vf, o[f], 0, 0, 0);
      }
    }
    __syncthreads();
  }

#pragma unroll
  for (int f = 0; f < 8; ++f)
#pragma unroll
    for (int r = 0; r < 4; ++r) {
      float val = o[f][r] / lrow[r];
      y[(size_t)(b * 2048 + rq + r) * 2048 + h * 128 + f * 16 + lr] = f2b(val);
    }
}

// ---------------- launch ----------------

extern "C" void kernel_launch(void* const* d_in, const int* in_sizes, int n_in,
                              void* d_out, int out_size, void* d_ws, size_t ws_size,
                              hipStream_t stream) {
  const float* x  = (const float*)d_in[0];
  const float* Wq = (const float*)d_in[1];
  const float* bq = (const float*)d_in[2];
  const float* Wk = (const float*)d_in[3];
  const float* bk = (const float*)d_in[4];
  const float* Wv = (const float*)d_in[5];
  const float* bv = (const float*)d_in[6];
  const float* Wo = (const float*)d_in[7];
  const float* bo = (const float*)d_in[8];
  float* out = (float*)d_out;
  char* ws = (char*)d_ws;

  u16* xb  = (u16*)(ws + 0);          // 16 MB; reused as yb after QKV GEMM
  u16* Wt  = (u16*)(ws + 16777216);   // 24 MB; reused as Wot after QKV GEMM
  u16* qb  = (u16*)(ws + 41943040);   // 16 MB
  u16* kb  = (u16*)(ws + 58720256);   // 16 MB
  u16* vb  = (u16*)(ws + 75497472);   // 16 MB (total 88 MB)
  u16* Wot = Wt;
  u16* yb  = xb;

  cast_x_kernel<<<8192, 256, 0, stream>>>(x, xb, M_TOT * D_MODEL);
  trans_wqkv_kernel<<<dim3(32, 48), 256, 0, stream>>>(Wq, Wk, Wv, Wt);
  gemm_kernel<0><<<dim3(N_QKV / 128, M_TOT / 128), 256, 0, stream>>>(
      xb, Wt, qb, kb, vb, bq, bk, bv, nullptr, nullptr);
  trans_wo_kernel<<<dim3(32, 16), 256, 0, stream>>>(Wo, Wot);
  attn_kernel<<<dim3(SEQ / 64, N_HEADS, BATCH), 256, 0, stream>>>(qb, kb, vb, yb);
  gemm_kernel<1><<<dim3(D_MODEL / 128, M_TOT / 128), 256, 0, stream>>>(
      yb, Wot, nullptr, nullptr, nullptr, nullptr, nullptr, nullptr, out, bo);
}

// Round 2
// 449.219 us; speedup vs baseline: 1.5101x; 1.5101x over previous
//
#include <hip/hip_runtime.h>
#include <stdint.h>

typedef unsigned short u16;
typedef __attribute__((ext_vector_type(4))) u16 u16x4;
typedef __attribute__((ext_vector_type(8))) u16 u16x8;
typedef __attribute__((ext_vector_type(8))) __bf16 bf16x8;
typedef __attribute__((ext_vector_type(4))) float f32x4;

#define D_MODEL 2048
#define N_HEADS 16
#define HEAD_DIM 128
#define BATCH 2
#define SEQ 2048
#define M_TOT (BATCH*SEQ)          // 4096
#define N_QKV (3*D_MODEL)          // 6144

__device__ __forceinline__ u16 f2b(float f) {
  union { float f; uint32_t u; } c; c.f = f;
  uint32_t u = c.u;
  uint32_t r = (u + 0x7fffu + ((u >> 16) & 1u)) >> 16;
  return (u16)r;
}

__device__ __forceinline__ void gl_lds16(const u16* g, u16* l) {
  __builtin_amdgcn_global_load_lds(
      (const __attribute__((address_space(1))) uint32_t*)g,
      (__attribute__((address_space(3))) uint32_t*)l, 16, 0, 0);
}

// ---------------- prep kernels ----------------

__global__ void cast_x_kernel(const float* __restrict__ x, u16* __restrict__ xb, int n) {
  int i = (blockIdx.x * blockDim.x + threadIdx.x) * 4;
  if (i >= n) return;
  f32x4 v = *(const f32x4*)(x + i);
  u16x4 o;
  o[0] = f2b(v[0]); o[1] = f2b(v[1]); o[2] = f2b(v[2]); o[3] = f2b(v[3]);
  *(u16x4*)(xb + i) = o;
}

// Wq/Wk/Wv [H][2048][128] f32  ->  Wt [6144][2048] bf16, row n=(qkv*2048+h*128+d), K-major
__global__ void trans_wqkv_kernel(const float* __restrict__ Wq, const float* __restrict__ Wk,
                                  const float* __restrict__ Wv, u16* __restrict__ Wt) {
  __shared__ u16 Tl[128][72];
  const int hh = blockIdx.y;           // 0..47 = qkv*16+h
  const int qkv = hh >> 4, h = hh & 15;
  const float* src = (qkv == 0 ? Wq : qkv == 1 ? Wk : Wv) + (size_t)h * 2048 * 128;
  const int k0 = blockIdx.x * 64;
  const int tid = threadIdx.x;
  for (int it = 0; it < 32; ++it) {
    int idx = it * 256 + tid;
    int k = idx >> 7, d = idx & 127;
    Tl[d][k] = f2b(src[(size_t)(k0 + k) * 128 + d]);
  }
  __syncthreads();
  for (int it = 0; it < 32; ++it) {
    int idx = it * 256 + tid;
    int d = idx >> 6, kk = idx & 63;
    Wt[(size_t)(hh * 128 + d) * 2048 + k0 + kk] = Tl[d][kk];
  }
}

// Wo [2048][2048] f32 -> Wot [2048][2048] bf16 (transposed, K-major)
__global__ void trans_wo_kernel(const float* __restrict__ Wo, u16* __restrict__ Wot) {
  __shared__ u16 Tl[128][72];
  const int k0 = blockIdx.x * 64;     // 32 tiles
  const int n0 = blockIdx.y * 128;    // 16 tiles
  const int tid = threadIdx.x;
  for (int it = 0; it < 32; ++it) {
    int idx = it * 256 + tid;
    int k = idx >> 7, n = idx & 127;
    Tl[n][k] = f2b(Wo[(size_t)(k0 + k) * 2048 + n0 + n]);
  }
  __syncthreads();
  for (int it = 0; it < 32; ++it) {
    int idx = it * 256 + tid;
    int d = idx >> 6, kk = idx & 63;
    Wot[(size_t)(n0 + d) * 2048 + k0 + kk] = Tl[d][kk];
  }
}

// vb [B,H,T,128] bf16 -> vt [B,H,128,T] bf16
__global__ void transpose_v_kernel(const u16* __restrict__ vb, u16* __restrict__ vt) {
  __shared__ u16 Tl[128 * 65];
  const int bh = blockIdx.y;
  const int t0 = blockIdx.x * 64;
  const int tid = threadIdx.x;
  const u16* src = vb + (size_t)bh * 2048 * 128;
  u16* dstp = vt + (size_t)bh * 128 * 2048;
#pragma unroll
  for (int c = 0; c < 4; ++c) {
    int ci = c * 256 + tid;
    int tr = ci >> 4, d0 = (ci & 15) * 8;
    u16x8 v = *(const u16x8*)(src + (size_t)(t0 + tr) * 128 + d0);
#pragma unroll
    for (int e = 0; e < 8; ++e) Tl[(d0 + e) * 65 + tr] = v[e];
  }
  __syncthreads();
#pragma unroll
  for (int it = 0; it < 32; ++it) {
    int idx = it * 256 + tid;
    int d = idx >> 6, tt = idx & 63;
    dstp[(size_t)d * 2048 + t0 + tt] = Tl[d * 65 + tt];
  }
}

// ---------------- GEMM (128x128 tile, BK=32, 4 waves, m97 structure) ----------------
template <int EPI>
__global__ __launch_bounds__(256) void gemm_kernel(
    const u16* __restrict__ A, const u16* __restrict__ B,
    u16* __restrict__ qo, u16* __restrict__ ko, u16* __restrict__ vo,
    const float* __restrict__ bq, const float* __restrict__ bk, const float* __restrict__ bv,
    float* __restrict__ outf, const float* __restrict__ bo) {
  __shared__ u16 As[128 * 32];
  __shared__ u16 Bs[128 * 32];
  const int tid = threadIdx.x;
  const int lane = tid & 63, wv = tid >> 6;
  const int m0 = blockIdx.y * 128, n0 = blockIdx.x * 128;
  const int wm = (wv >> 1) * 64, wn = (wv & 1) * 64;
  const int lr = lane & 15, lk = (lane >> 4) * 8;

  f32x4 zero = {0.f, 0.f, 0.f, 0.f};
  f32x4 acc[4][4];
#pragma unroll
  for (int i = 0; i < 4; ++i)
#pragma unroll
    for (int j = 0; j < 4; ++j) acc[i][j] = zero;

  const int e0 = tid * 8;
  const int row0 = e0 >> 5;
  const int col0 = e0 & 31;
  const u16* Ag = A + (size_t)(m0 + row0) * 2048 + col0;
  const u16* Bg = B + (size_t)(n0 + row0) * 2048 + col0;

  for (int kt = 0; kt < 2048; kt += 32) {
    gl_lds16(Ag + kt, As + e0);
    gl_lds16(Ag + kt + (size_t)64 * 2048, As + e0 + 64 * 32);
    gl_lds16(Bg + kt, Bs + e0);
    gl_lds16(Bg + kt + (size_t)64 * 2048, Bs + e0 + 64 * 32);
    __syncthreads();
    bf16x8 af[4], bfm[4];
#pragma unroll
    for (int i = 0; i < 4; ++i) af[i] = *(const bf16x8*)(As + (wm + i * 16 + lr) * 32 + lk);
#pragma unroll
    for (int j = 0; j < 4; ++j) bfm[j] = *(const bf16x8*)(Bs + (wn + j * 16 + lr) * 32 + lk);
#pragma unroll
    for (int i = 0; i < 4; ++i)
#pragma unroll
      for (int j = 0; j < 4; ++j)
        acc[i][j] = __builtin_amdgcn_mfma_f32_16x16x32_bf16(af[i], bfm[j], acc[i][j], 0, 0, 0);
    __syncthreads();
  }

  const int rbase = (lane >> 4) * 4;
  if (EPI == 0) {
    const int qkv = n0 >> 11, h = (n0 >> 7) & 15;
    const float* bias = (qkv == 0) ? bq : (qkv == 1) ? bk : bv;
    u16* dst = (qkv == 0) ? qo : (qkv == 1) ? ko : vo;
#pragma unroll
    for (int i = 0; i < 4; ++i)
#pragma unroll
      for (int j = 0; j < 4; ++j)
#pragma unroll
        for (int r = 0; r < 4; ++r) {
          int gm = m0 + wm + i * 16 + rbase + r;
          int d = wn + j * 16 + (lane & 15);
          float val = acc[i][j][r] + bias[h * 128 + d];
          int b = gm >> 11, t = gm & 2047;
          dst[((size_t)(b * 16 + h) * 2048 + t) * 128 + d] = f2b(val);
        }
  } else {
#pragma unroll
    for (int i = 0; i < 4; ++i)
#pragma unroll
      for (int j = 0; j < 4; ++j)
#pragma unroll
        for (int r = 0; r < 4; ++r) {
          int gm = m0 + wm + i * 16 + rbase + r;
          int gn = n0 + wn + j * 16 + (lane & 15);
          outf[(size_t)gm * 2048 + gn] = acc[i][j][r] + bo[gn];
        }
  }
}

// ---------------- flash attention (causal) ----------------
// grid (16, H, B); Q-tile 128 rows, 4 waves x 32 rows; KV tile 64, double-buffered.
// K LDS [64][128], V^T LDS [128][64], P LDS [32][64]/wave -- all XOR-swizzled
// (byte ^= (row&7)<<4); K/V staged via global_load_lds with pre-swizzled source.
__global__ __launch_bounds__(256) void attn_kernel(
    const u16* __restrict__ qg, const u16* __restrict__ kg,
    const u16* __restrict__ vtg, u16* __restrict__ y) {
  __shared__ u16 Kb[2][64 * 128];
  __shared__ u16 Vb[2][128 * 64];
  __shared__ u16 Pl[4][32 * 64];
  const int tid = threadIdx.x, lane = tid & 63, w = tid >> 6;
  const int b = blockIdx.z, h = blockIdx.y;
  const int qt = b ? (15 - (int)blockIdx.x) : (int)blockIdx.x;  // load-balance hedge
  const int q0 = qt * 128;
  const int lr = lane & 15, lk = (lane >> 4) * 8;
  const size_t bh = (size_t)b * 16 + h;
  const u16* Qp = qg + bh * (2048 * 128);
  const u16* Kp = kg + bh * (2048 * 128);
  const u16* Vp = vtg + bh * (128 * 2048);

  const int qw = q0 + w * 32;
  bf16x8 qf[2][4];
#pragma unroll
  for (int s = 0; s < 2; ++s)
#pragma unroll
    for (int i = 0; i < 4; ++i)
      qf[s][i] = *(const bf16x8*)(Qp + (size_t)(qw + s * 16 + lr) * 128 + i * 32 + lk);

  f32x4 zero = {0.f, 0.f, 0.f, 0.f};
  f32x4 o[2][8];
#pragma unroll
  for (int s = 0; s < 2; ++s)
#pragma unroll
    for (int f = 0; f < 8; ++f) o[s][f] = zero;
  float mrow[2][4], lrow[2][4];
#pragma unroll
  for (int s = 0; s < 2; ++s)
#pragma unroll
    for (int r = 0; r < 4; ++r) { mrow[s][r] = -1e30f; lrow[s][r] = 0.f; }

  // staging: linear LDS dest chunk ci holds global chunk with XOR'd column index
  int koff[4], voff[4], dstc[4];
#pragma unroll
  for (int c = 0; c < 4; ++c) {
    int ci = c * 256 + tid;
    dstc[c] = ci * 8;
    int kr = ci >> 4, kj = ci & 15;                 // K tile: 64 rows x 16 chunks
    koff[c] = kr * 128 + (kj ^ (kr & 7)) * 8;
    int vd = ci >> 3, vj = ci & 7;                  // V^T tile: 128 rows x 8 chunks
    voff[c] = vd * 2048 + (vj ^ (vd & 7)) * 8;
  }

  const int kxor = (lr & 7) << 4;
  const int nt = (q0 >> 6) + 2;

#pragma unroll
  for (int c = 0; c < 4; ++c) gl_lds16(Kp + koff[c], Kb[0] + dstc[c]);
#pragma unroll
  for (int c = 0; c < 4; ++c) gl_lds16(Vp + voff[c], Vb[0] + dstc[c]);
  __syncthreads();

  const float scale = 0.08838834764831845f;  // 1/sqrt(128)
  const int rbase = (lane >> 4) * 4;
  int cur = 0;

  for (int t = 0; t < nt; ++t) {
    const int s0 = t * 64;
    if (t + 1 < nt) {
      const size_t skn = (size_t)(s0 + 64) * 128;
#pragma unroll
      for (int c = 0; c < 4; ++c) gl_lds16(Kp + skn + koff[c], Kb[cur ^ 1] + dstc[c]);
#pragma unroll
      for (int c = 0; c < 4; ++c) gl_lds16(Vp + (s0 + 64) + voff[c], Vb[cur ^ 1] + dstc[c]);
    }
    if (s0 <= qw + 31) {
      const char* Kc = (const char*)Kb[cur];
      f32x4 sf[2][4];
#pragma unroll
      for (int sj = 0; sj < 4; ++sj) {
        f32x4 a0 = zero, a1 = zero;
#pragma unroll
        for (int i = 0; i < 4; ++i) {
          bf16x8 kf = *(const bf16x8*)(Kc + ((((sj * 16 + lr) * 256) + (i * 32 + lk) * 2) ^ kxor));
          a0 = __builtin_amdgcn_mfma_f32_16x16x32_bf16(qf[0][i], kf, a0, 0, 0, 0);
          a1 = __builtin_amdgcn_mfma_f32_16x16x32_bf16(qf[1][i], kf, a1, 0, 0, 0);
        }
        sf[0][sj] = a0; sf[1][sj] = a1;
      }
      char* Pc = (char*)Pl[w];
      float sfac[2][4];
#pragma unroll
      for (int s = 0; s < 2; ++s) {
#pragma unroll
        for (int r = 0; r < 4; ++r) {
          const int rq = qw + s * 16 + rbase + r;
          float pm = -1e30f;
#pragma unroll
          for (int sj = 0; sj < 4; ++sj) {
            float val = sf[s][sj][r] * scale;
            if (s0 + sj * 16 + lr > rq) val = -1e30f;
            sf[s][sj][r] = val;
            pm = fmaxf(pm, val);
          }
          pm = fmaxf(pm, __shfl_xor(pm, 1));
          pm = fmaxf(pm, __shfl_xor(pm, 2));
          pm = fmaxf(pm, __shfl_xor(pm, 4));
          pm = fmaxf(pm, __shfl_xor(pm, 8));
          float mnew = fmaxf(mrow[s][r], pm);
          sfac[s][r] = __expf(mrow[s][r] - mnew);
          mrow[s][r] = mnew;
          const int prow = s * 16 + rbase + r;
          const int pxor = (prow & 7) << 4;
          float ps = 0.f;
#pragma unroll
          for (int sj = 0; sj < 4; ++sj) {
            float p = __expf(sf[s][sj][r] - mnew);
            ps += p;
            *(u16*)(Pc + (((prow * 128) + (sj * 16 + lr) * 2) ^ pxor)) = f2b(p);
          }
          ps += __shfl_xor(ps, 1);
          ps += __shfl_xor(ps, 2);
          ps += __shfl_xor(ps, 4);
          ps += __shfl_xor(ps, 8);
          lrow[s][r] = lrow[s][r] * sfac[s][r] + ps;
        }
#pragma unroll
        for (int f = 0; f < 8; ++f)
#pragma unroll
          for (int r = 0; r < 4; ++r) o[s][f][r] *= sfac[s][r];
      }
      const char* Vc = (const char*)Vb[cur];
#pragma unroll
      for (int st = 0; st < 2; ++st) {
        bf16x8 pf0 = *(const bf16x8*)(Pc + (((lr * 128) + (st * 32 + lk) * 2) ^ kxor));
        bf16x8 pf1 = *(const bf16x8*)(Pc + ((((16 + lr) * 128) + (st * 32 + lk) * 2) ^ kxor));
#pragma unroll
        for (int f = 0; f < 8; ++f) {
          bf16x8 vf = *(const bf16x8*)(Vc + ((((f * 16 + lr) * 128) + (st * 32 + lk) * 2) ^ kxor));
          o[0][f] = __builtin_amdgcn_mfma_f32_16x16x32_bf16(pf0, vf, o[0][f], 0, 0, 0);
          o[1][f] = __builtin_amdgcn_mfma_f32_16x16x32_bf16(pf1, vf, o[1][f], 0, 0, 0);
        }
      }
    }
    __syncthreads();
    cur ^= 1;
  }

#pragma unroll
  for (int s = 0; s < 2; ++s)
#pragma unroll
    for (int f = 0; f < 8; ++f)
#pragma unroll
      for (int r = 0; r < 4; ++r) {
        const int row = qw + s * 16 + rbase + r;
        y[((size_t)b * 2048 + row) * 2048 + h * 128 + f * 16 + lr] =
            f2b(o[s][f][r] / lrow[s][r]);
      }
}

// ---------------- launch ----------------

extern "C" void kernel_launch(void* const* d_in, const int* in_sizes, int n_in,
                              void* d_out, int out_size, void* d_ws, size_t ws_size,
                              hipStream_t stream) {
  const float* x  = (const float*)d_in[0];
  const float* Wq = (const float*)d_in[1];
  const float* bq = (const float*)d_in[2];
  const float* Wk = (const float*)d_in[3];
  const float* bk = (const float*)d_in[4];
  const float* Wv = (const float*)d_in[5];
  const float* bv = (const float*)d_in[6];
  const float* Wo = (const float*)d_in[7];
  const float* bo = (const float*)d_in[8];
  float* out = (float*)d_out;
  char* ws = (char*)d_ws;

  u16* xb  = (u16*)(ws + 0);          // 16 MB; reused as yb after QKV GEMM
  u16* Wt  = (u16*)(ws + 16777216);   // 24 MB; front 8 MB reused as Wot, next 16 MB as vtb
  u16* qb  = (u16*)(ws + 41943040);   // 16 MB
  u16* kb  = (u16*)(ws + 58720256);   // 16 MB
  u16* vb  = (u16*)(ws + 75497472);   // 16 MB (total 88 MB)
  u16* Wot = Wt;                      // [2048][2048] bf16 = 8 MB
  u16* vtb = (u16*)(ws + 25165824);   // [B,H,128,T] bf16 = 16 MB
  u16* yb  = xb;

  cast_x_kernel<<<8192, 256, 0, stream>>>(x, xb, M_TOT * D_MODEL);
  trans_wqkv_kernel<<<dim3(32, 48), 256, 0, stream>>>(Wq, Wk, Wv, Wt);
  gemm_kernel<0><<<dim3(N_QKV / 128, M_TOT / 128), 256, 0, stream>>>(
      xb, Wt, qb, kb, vb, bq, bk, bv, nullptr, nullptr);
  trans_wo_kernel<<<dim3(32, 16), 256, 0, stream>>>(Wo, Wot);
  transpose_v_kernel<<<dim3(32, 32), 256, 0, stream>>>(vb, vtb);
  attn_kernel<<<dim3(16, N_HEADS, BATCH), 256, 0, stream>>>(qb, kb, vtb, yb);
  gemm_kernel<1><<<dim3(D_MODEL / 128, M_TOT / 128), 256, 0, stream>>>(
      yb, Wot, nullptr, nullptr, nullptr, nullptr, nullptr, nullptr, out, bo);
}

// Round 3
// 343.223 us; speedup vs baseline: 1.9764x; 1.3088x over previous
//
#include <hip/hip_runtime.h>
#include <stdint.h>

typedef unsigned short u16;
typedef __attribute__((ext_vector_type(4))) u16 u16x4;
typedef __attribute__((ext_vector_type(8))) u16 u16x8;
typedef __attribute__((ext_vector_type(8))) __bf16 bf16x8;
typedef __attribute__((ext_vector_type(4))) float f32x4;

#define D_MODEL 2048
#define N_HEADS 16
#define HEAD_DIM 128
#define BATCH 2
#define SEQ 2048
#define M_TOT (BATCH*SEQ)          // 4096
#define N_QKV (3*D_MODEL)          // 6144

__device__ __forceinline__ u16 f2b(float f) {
  union { float f; uint32_t u; } c; c.f = f;
  uint32_t u = c.u;
  uint32_t r = (u + 0x7fffu + ((u >> 16) & 1u)) >> 16;
  return (u16)r;
}

__device__ __forceinline__ void gl_lds16(const u16* g, u16* l) {
  __builtin_amdgcn_global_load_lds(
      (const __attribute__((address_space(1))) uint32_t*)g,
      (__attribute__((address_space(3))) uint32_t*)l, 16, 0, 0);
}

// ---------------- prep kernels ----------------

__global__ void cast_x_kernel(const float* __restrict__ x, u16* __restrict__ xb, int n) {
  int i = (blockIdx.x * blockDim.x + threadIdx.x) * 4;
  if (i >= n) return;
  f32x4 v = *(const f32x4*)(x + i);
  u16x4 o;
  o[0] = f2b(v[0]); o[1] = f2b(v[1]); o[2] = f2b(v[2]); o[3] = f2b(v[3]);
  *(u16x4*)(xb + i) = o;
}

// Wq/Wk/Wv [H][2048][128] f32  ->  Wt [6144][2048] bf16, row n=(qkv*2048+h*128+d), K-major
__global__ void trans_wqkv_kernel(const float* __restrict__ Wq, const float* __restrict__ Wk,
                                  const float* __restrict__ Wv, u16* __restrict__ Wt) {
  __shared__ u16 Tl[128][72];
  const int hh = blockIdx.y;           // 0..47 = qkv*16+h
  const int qkv = hh >> 4, h = hh & 15;
  const float* src = (qkv == 0 ? Wq : qkv == 1 ? Wk : Wv) + (size_t)h * 2048 * 128;
  const int k0 = blockIdx.x * 64;
  const int tid = threadIdx.x;
  for (int it = 0; it < 32; ++it) {
    int idx = it * 256 + tid;
    int k = idx >> 7, d = idx & 127;
    Tl[d][k] = f2b(src[(size_t)(k0 + k) * 128 + d]);
  }
  __syncthreads();
  for (int it = 0; it < 32; ++it) {
    int idx = it * 256 + tid;
    int d = idx >> 6, kk = idx & 63;
    Wt[(size_t)(hh * 128 + d) * 2048 + k0 + kk] = Tl[d][kk];
  }
}

// Wo [2048][2048] f32 -> Wot [2048][2048] bf16 (transposed, K-major)
__global__ void trans_wo_kernel(const float* __restrict__ Wo, u16* __restrict__ Wot) {
  __shared__ u16 Tl[128][72];
  const int k0 = blockIdx.x * 64;     // 32 tiles
  const int n0 = blockIdx.y * 128;    // 16 tiles
  const int tid = threadIdx.x;
  for (int it = 0; it < 32; ++it) {
    int idx = it * 256 + tid;
    int k = idx >> 7, n = idx & 127;
    Tl[n][k] = f2b(Wo[(size_t)(k0 + k) * 2048 + n0 + n]);
  }
  __syncthreads();
  for (int it = 0; it < 32; ++it) {
    int idx = it * 256 + tid;
    int d = idx >> 6, kk = idx & 63;
    Wot[(size_t)(n0 + d) * 2048 + k0 + kk] = Tl[d][kk];
  }
}

// vb [B,H,T,128] bf16 -> vt [B,H,128,T] bf16
__global__ void transpose_v_kernel(const u16* __restrict__ vb, u16* __restrict__ vt) {
  __shared__ u16 Tl[128 * 65];
  const int bh = blockIdx.y;
  const int t0 = blockIdx.x * 64;
  const int tid = threadIdx.x;
  const u16* src = vb + (size_t)bh * 2048 * 128;
  u16* dstp = vt + (size_t)bh * 128 * 2048;
#pragma unroll
  for (int c = 0; c < 4; ++c) {
    int ci = c * 256 + tid;
    int tr = ci >> 4, d0 = (ci & 15) * 8;
    u16x8 v = *(const u16x8*)(src + (size_t)(t0 + tr) * 128 + d0);
#pragma unroll
    for (int e = 0; e < 8; ++e) Tl[(d0 + e) * 65 + tr] = v[e];
  }
  __syncthreads();
#pragma unroll
  for (int it = 0; it < 32; ++it) {
    int idx = it * 256 + tid;
    int d = idx >> 6, tt = idx & 63;
    dstp[(size_t)d * 2048 + t0 + tt] = Tl[d * 65 + tt];
  }
}

// ---------------- GEMM (128x128 tile, BK=32, 4 waves, m97 structure) ----------------
// 1D grid with XCD-chunked swizzle (nwg % 8 == 0). EPI 0: QKV epilogue
// (scatter + bias, Q pre-scaled by 1/sqrt(128)*log2e). EPI 1: f32 out + bo.
template <int EPI>
__global__ __launch_bounds__(256) void gemm_kernel(
    const u16* __restrict__ A, const u16* __restrict__ B,
    u16* __restrict__ qo, u16* __restrict__ ko, u16* __restrict__ vo,
    const float* __restrict__ bq, const float* __restrict__ bk, const float* __restrict__ bv,
    float* __restrict__ outf, const float* __restrict__ bo) {
  __shared__ u16 As[128 * 32];
  __shared__ u16 Bs[128 * 32];
  constexpr int NX = (EPI == 0) ? 48 : 16;
  const int nwg = gridDim.x;
  const int q8 = nwg >> 3;
  const int bid0 = blockIdx.x;
  const int gid = (bid0 & 7) * q8 + (bid0 >> 3);   // XCD-chunked, bijective
  const int m0 = (gid / NX) * 128, n0 = (gid % NX) * 128;

  const int tid = threadIdx.x;
  const int lane = tid & 63, wv = tid >> 6;
  const int wm = (wv >> 1) * 64, wn = (wv & 1) * 64;
  const int lr = lane & 15, lk = (lane >> 4) * 8;

  f32x4 zero = {0.f, 0.f, 0.f, 0.f};
  f32x4 acc[4][4];
#pragma unroll
  for (int i = 0; i < 4; ++i)
#pragma unroll
    for (int j = 0; j < 4; ++j) acc[i][j] = zero;

  const int e0 = tid * 8;
  const int row0 = e0 >> 5;
  const int col0 = e0 & 31;
  const u16* Ag = A + (size_t)(m0 + row0) * 2048 + col0;
  const u16* Bg = B + (size_t)(n0 + row0) * 2048 + col0;

  for (int kt = 0; kt < 2048; kt += 32) {
    gl_lds16(Ag + kt, As + e0);
    gl_lds16(Ag + kt + (size_t)64 * 2048, As + e0 + 64 * 32);
    gl_lds16(Bg + kt, Bs + e0);
    gl_lds16(Bg + kt + (size_t)64 * 2048, Bs + e0 + 64 * 32);
    __syncthreads();
    bf16x8 af[4], bfm[4];
#pragma unroll
    for (int i = 0; i < 4; ++i) af[i] = *(const bf16x8*)(As + (wm + i * 16 + lr) * 32 + lk);
#pragma unroll
    for (int j = 0; j < 4; ++j) bfm[j] = *(const bf16x8*)(Bs + (wn + j * 16 + lr) * 32 + lk);
#pragma unroll
    for (int i = 0; i < 4; ++i)
#pragma unroll
      for (int j = 0; j < 4; ++j)
        acc[i][j] = __builtin_amdgcn_mfma_f32_16x16x32_bf16(af[i], bfm[j], acc[i][j], 0, 0, 0);
    __syncthreads();
  }

  const int rbase = (lane >> 4) * 4;
  if (EPI == 0) {
    const int qkv = n0 >> 11, h = (n0 >> 7) & 15;
    const float* bias = (qkv == 0) ? bq : (qkv == 1) ? bk : bv;
    u16* dst = (qkv == 0) ? qo : (qkv == 1) ? ko : vo;
    const float qscale = 0.08838834764831845f * 1.4426950408889634f;  // 1/sqrt(128)*log2e
#pragma unroll
    for (int i = 0; i < 4; ++i)
#pragma unroll
      for (int j = 0; j < 4; ++j)
#pragma unroll
        for (int r = 0; r < 4; ++r) {
          int gm = m0 + wm + i * 16 + rbase + r;
          int d = wn + j * 16 + (lane & 15);
          float val = acc[i][j][r] + bias[h * 128 + d];
          if (qkv == 0) val *= qscale;
          int b = gm >> 11, t = gm & 2047;
          dst[((size_t)(b * 16 + h) * 2048 + t) * 128 + d] = f2b(val);
        }
  } else {
#pragma unroll
    for (int i = 0; i < 4; ++i)
#pragma unroll
      for (int j = 0; j < 4; ++j)
#pragma unroll
        for (int r = 0; r < 4; ++r) {
          int gm = m0 + wm + i * 16 + rbase + r;
          int gn = n0 + wn + j * 16 + (lane & 15);
          outf[(size_t)gm * 2048 + gn] = acc[i][j][r] + bo[gn];
        }
  }
}

// ---------------- flash attention (causal) ----------------
// 256 blocks of 256 threads. Block bid: bh = bid&31 (XCD-grouped), px = bid>>5.
// Block processes Q-tiles qt = px and 15-px sequentially -> exactly 34 KV-tiles
// per block (perfect static balance). 4 waves x 32 q-rows. KV tile 64, dbuf.
// K/V/P LDS XOR-swizzled (byte ^= (row&7)<<4), staged pre-swizzled for gl_lds.
// Q arrives pre-scaled by 1/sqrt(128)*log2e -> scores in exp2 domain.
__global__ __launch_bounds__(256) void attn_kernel(
    const u16* __restrict__ qg, const u16* __restrict__ kg,
    const u16* __restrict__ vtg, u16* __restrict__ y) {
  __shared__ u16 Kb[2][64 * 128];
  __shared__ u16 Vb[2][128 * 64];
  __shared__ u16 Pl[4][32 * 64];
  const int tid = threadIdx.x, lane = tid & 63, w = tid >> 6;
  const int bid = blockIdx.x;
  const int bh = bid & 31, px = bid >> 5;
  const int b = bh >> 4, h = bh & 15;
  const int lr = lane & 15, lk = (lane >> 4) * 8;
  const u16* Qp = qg + (size_t)bh * (2048 * 128);
  const u16* Kp = kg + (size_t)bh * (2048 * 128);
  const u16* Vp = vtg + (size_t)bh * (128 * 2048);

  int koff[4], voff[4], dstc[4];
#pragma unroll
  for (int c = 0; c < 4; ++c) {
    int ci = c * 256 + tid;
    dstc[c] = ci * 8;
    int kr = ci >> 4, kj = ci & 15;                 // K tile: 64 rows x 16 chunks
    koff[c] = kr * 128 + (kj ^ (kr & 7)) * 8;
    int vd = ci >> 3, vj = ci & 7;                  // V^T tile: 128 rows x 8 chunks
    voff[c] = vd * 2048 + (vj ^ (vd & 7)) * 8;
  }
  const int kxor = (lr & 7) << 4;
  const int rbase = (lane >> 4) * 4;
  const f32x4 zero = {0.f, 0.f, 0.f, 0.f};

  for (int pi = 0; pi < 2; ++pi) {
    const int qt = pi ? (15 - px) : px;
    const int q0 = qt * 128;
    const int qw = q0 + w * 32;
    const int nt = 2 * qt + 2;

    bf16x8 qf[2][4];
#pragma unroll
    for (int s = 0; s < 2; ++s)
#pragma unroll
      for (int i = 0; i < 4; ++i)
        qf[s][i] = *(const bf16x8*)(Qp + (size_t)(qw + s * 16 + lr) * 128 + i * 32 + lk);

    f32x4 o[2][8];
#pragma unroll
    for (int s = 0; s < 2; ++s)
#pragma unroll
      for (int f = 0; f < 8; ++f) o[s][f] = zero;
    float mrow[2][4], lrow[2][4];
#pragma unroll
    for (int s = 0; s < 2; ++s)
#pragma unroll
      for (int r = 0; r < 4; ++r) { mrow[s][r] = -1e30f; lrow[s][r] = 0.f; }

    // prologue: stage tile 0
#pragma unroll
    for (int c = 0; c < 4; ++c) gl_lds16(Kp + koff[c], Kb[0] + dstc[c]);
#pragma unroll
    for (int c = 0; c < 4; ++c) gl_lds16(Vp + voff[c], Vb[0] + dstc[c]);
    __syncthreads();

    int cur = 0;
    for (int t = 0; t < nt; ++t) {
      const int s0 = t * 64;
      if (t + 1 < nt) {
        const size_t skn = (size_t)(s0 + 64) * 128;
#pragma unroll
        for (int c = 0; c < 4; ++c) gl_lds16(Kp + skn + koff[c], Kb[cur ^ 1] + dstc[c]);
#pragma unroll
        for (int c = 0; c < 4; ++c) gl_lds16(Vp + (s0 + 64) + voff[c], Vb[cur ^ 1] + dstc[c]);
      }
      if (s0 <= qw + 31) {
        const char* Kc = (const char*)Kb[cur];
        f32x4 sf[2][4];
#pragma unroll
        for (int sj = 0; sj < 4; ++sj) {
          f32x4 a0 = zero, a1 = zero;
#pragma unroll
          for (int i = 0; i < 4; ++i) {
            bf16x8 kf = *(const bf16x8*)(Kc + ((((sj * 16 + lr) * 256) + (i * 32 + lk) * 2) ^ kxor));
            a0 = __builtin_amdgcn_mfma_f32_16x16x32_bf16(qf[0][i], kf, a0, 0, 0, 0);
            a1 = __builtin_amdgcn_mfma_f32_16x16x32_bf16(qf[1][i], kf, a1, 0, 0, 0);
          }
          sf[0][sj] = a0; sf[1][sj] = a1;
        }

        char* Pc = (char*)Pl[w];
        const bool masked = (s0 + 63 > qw);          // wave-uniform: diagonal tile
        float pmax[2][4];
        bool need = false;
#pragma unroll
        for (int s = 0; s < 2; ++s)
#pragma unroll
          for (int r = 0; r < 4; ++r) {
            if (masked) {
              const int rq = qw + s * 16 + rbase + r;
#pragma unroll
              for (int sj = 0; sj < 4; ++sj)
                if (s0 + sj * 16 + lr > rq) sf[s][sj][r] = -1e30f;
            }
            float pm = fmaxf(fmaxf(sf[s][0][r], sf[s][1][r]),
                             fmaxf(sf[s][2][r], sf[s][3][r]));
            pm = fmaxf(pm, __shfl_xor(pm, 1));
            pm = fmaxf(pm, __shfl_xor(pm, 2));
            pm = fmaxf(pm, __shfl_xor(pm, 4));
            pm = fmaxf(pm, __shfl_xor(pm, 8));
            pmax[s][r] = pm;
            need |= (pm > mrow[s][r] + 8.f);
          }
        if (__any(need)) {                            // defer-max: rescale rarely
#pragma unroll
          for (int s = 0; s < 2; ++s) {
            float sfac[4];
#pragma unroll
            for (int r = 0; r < 4; ++r) {
              float mnew = fmaxf(mrow[s][r], pmax[s][r]);
              sfac[r] = __builtin_amdgcn_exp2f(mrow[s][r] - mnew);
              mrow[s][r] = mnew;
              lrow[s][r] *= sfac[r];
            }
#pragma unroll
            for (int f = 0; f < 8; ++f)
#pragma unroll
              for (int r = 0; r < 4; ++r) o[s][f][r] *= sfac[r];
          }
        }
#pragma unroll
        for (int s = 0; s < 2; ++s)
#pragma unroll
          for (int r = 0; r < 4; ++r) {
            const int prow = s * 16 + rbase + r;
            const int pxor = (prow & 7) << 4;
            float ps = 0.f;
#pragma unroll
            for (int sj = 0; sj < 4; ++sj) {
              float p = __builtin_amdgcn_exp2f(sf[s][sj][r] - mrow[s][r]);
              ps += p;
              *(u16*)(Pc + (((prow * 128) + (sj * 16 + lr) * 2) ^ pxor)) = f2b(p);
            }
            ps += __shfl_xor(ps, 1);
            ps += __shfl_xor(ps, 2);
            ps += __shfl_xor(ps, 4);
            ps += __shfl_xor(ps, 8);
            lrow[s][r] += ps;
          }

        const char* Vc = (const char*)Vb[cur];
#pragma unroll
        for (int st = 0; st < 2; ++st) {
          bf16x8 pf0 = *(const bf16x8*)(Pc + (((lr * 128) + (st * 32 + lk) * 2) ^ kxor));
          bf16x8 pf1 = *(const bf16x8*)(Pc + ((((16 + lr) * 128) + (st * 32 + lk) * 2) ^ kxor));
#pragma unroll
          for (int f = 0; f < 8; ++f) {
            bf16x8 vf = *(const bf16x8*)(Vc + ((((f * 16 + lr) * 128) + (st * 32 + lk) * 2) ^ kxor));
            o[0][f] = __builtin_amdgcn_mfma_f32_16x16x32_bf16(pf0, vf, o[0][f], 0, 0, 0);
            o[1][f] = __builtin_amdgcn_mfma_f32_16x16x32_bf16(pf1, vf, o[1][f], 0, 0, 0);
          }
        }
      }
      __syncthreads();
      cur ^= 1;
    }

#pragma unroll
    for (int s = 0; s < 2; ++s)
#pragma unroll
      for (int r = 0; r < 4; ++r) {
        const float rinv = __builtin_amdgcn_rcpf(lrow[s][r]);
        const int row = qw + s * 16 + rbase + r;
#pragma unroll
        for (int f = 0; f < 8; ++f)
          y[((size_t)b * 2048 + row) * 2048 + h * 128 + f * 16 + lr] =
              f2b(o[s][f][r] * rinv);
      }
  }
}

// ---------------- launch ----------------

extern "C" void kernel_launch(void* const* d_in, const int* in_sizes, int n_in,
                              void* d_out, int out_size, void* d_ws, size_t ws_size,
                              hipStream_t stream) {
  const float* x  = (const float*)d_in[0];
  const float* Wq = (const float*)d_in[1];
  const float* bq = (const float*)d_in[2];
  const float* Wk = (const float*)d_in[3];
  const float* bk = (const float*)d_in[4];
  const float* Wv = (const float*)d_in[5];
  const float* bv = (const float*)d_in[6];
  const float* Wo = (const float*)d_in[7];
  const float* bo = (const float*)d_in[8];
  float* out = (float*)d_out;
  char* ws = (char*)d_ws;

  u16* xb  = (u16*)(ws + 0);          // 16 MB; reused as yb after QKV GEMM
  u16* Wt  = (u16*)(ws + 16777216);   // 24 MB; front 8 MB reused as Wot, next 16 MB as vtb
  u16* qb  = (u16*)(ws + 41943040);   // 16 MB
  u16* kb  = (u16*)(ws + 58720256);   // 16 MB
  u16* vb  = (u16*)(ws + 75497472);   // 16 MB (total 88 MB)
  u16* Wot = Wt;                      // [2048][2048] bf16 = 8 MB
  u16* vtb = (u16*)(ws + 25165824);   // [B,H,128,T] bf16 = 16 MB
  u16* yb  = xb;

  cast_x_kernel<<<8192, 256, 0, stream>>>(x, xb, M_TOT * D_MODEL);
  trans_wqkv_kernel<<<dim3(32, 48), 256, 0, stream>>>(Wq, Wk, Wv, Wt);
  gemm_kernel<0><<<N_QKV / 128 * (M_TOT / 128), 256, 0, stream>>>(
      xb, Wt, qb, kb, vb, bq, bk, bv, nullptr, nullptr);
  trans_wo_kernel<<<dim3(32, 16), 256, 0, stream>>>(Wo, Wot);
  transpose_v_kernel<<<dim3(32, 32), 256, 0, stream>>>(vb, vtb);
  attn_kernel<<<256, 256, 0, stream>>>(qb, kb, vtb, yb);
  gemm_kernel<1><<<D_MODEL / 128 * (M_TOT / 128), 256, 0, stream>>>(
      yb, Wot, nullptr, nullptr, nullptr, nullptr, nullptr, nullptr, out, bo);
}

// Round 4
// 306.508 us; speedup vs baseline: 2.2131x; 1.1198x over previous
//
#include <hip/hip_runtime.h>
#include <stdint.h>

typedef unsigned short u16;
typedef __attribute__((ext_vector_type(4))) u16 u16x4;
typedef __attribute__((ext_vector_type(8))) u16 u16x8;
typedef __attribute__((ext_vector_type(8))) __bf16 bf16x8;
typedef __attribute__((ext_vector_type(4))) float f32x4;

#define D_MODEL 2048
#define N_HEADS 16
#define HEAD_DIM 128
#define BATCH 2
#define SEQ 2048
#define M_TOT (BATCH*SEQ)          // 4096
#define N_QKV (3*D_MODEL)          // 6144

__device__ __forceinline__ u16 f2b(float f) {
  union { float f; uint32_t u; } c; c.f = f;
  uint32_t u = c.u;
  uint32_t r = (u + 0x7fffu + ((u >> 16) & 1u)) >> 16;
  return (u16)r;
}

__device__ __forceinline__ void gl_lds16(const u16* g, u16* l) {
  __builtin_amdgcn_global_load_lds(
      (const __attribute__((address_space(1))) uint32_t*)g,
      (__attribute__((address_space(3))) uint32_t*)l, 16, 0, 0);
}

// ---------------- prep kernels ----------------

__global__ void cast_x_kernel(const float* __restrict__ x, u16* __restrict__ xb, int n) {
  int i = (blockIdx.x * blockDim.x + threadIdx.x) * 4;
  if (i >= n) return;
  f32x4 v = *(const f32x4*)(x + i);
  u16x4 o;
  o[0] = f2b(v[0]); o[1] = f2b(v[1]); o[2] = f2b(v[2]); o[3] = f2b(v[3]);
  *(u16x4*)(xb + i) = o;
}

// Wq/Wk/Wv [H][2048][128] f32  ->  Wt [6144][2048] bf16, row n=(qkv*2048+h*128+d), K-major
__global__ void trans_wqkv_kernel(const float* __restrict__ Wq, const float* __restrict__ Wk,
                                  const float* __restrict__ Wv, u16* __restrict__ Wt) {
  __shared__ u16 Tl[128][72];
  const int hh = blockIdx.y;           // 0..47 = qkv*16+h
  const int qkv = hh >> 4, h = hh & 15;
  const float* src = (qkv == 0 ? Wq : qkv == 1 ? Wk : Wv) + (size_t)h * 2048 * 128;
  const int k0 = blockIdx.x * 64;
  const int tid = threadIdx.x;
  for (int it = 0; it < 32; ++it) {
    int idx = it * 256 + tid;
    int k = idx >> 7, d = idx & 127;
    Tl[d][k] = f2b(src[(size_t)(k0 + k) * 128 + d]);
  }
  __syncthreads();
  for (int it = 0; it < 32; ++it) {
    int idx = it * 256 + tid;
    int d = idx >> 6, kk = idx & 63;
    Wt[(size_t)(hh * 128 + d) * 2048 + k0 + kk] = Tl[d][kk];
  }
}

// Wo [2048][2048] f32 -> Wot [2048][2048] bf16 (transposed, K-major)
__global__ void trans_wo_kernel(const float* __restrict__ Wo, u16* __restrict__ Wot) {
  __shared__ u16 Tl[128][72];
  const int k0 = blockIdx.x * 64;     // 32 tiles
  const int n0 = blockIdx.y * 128;    // 16 tiles
  const int tid = threadIdx.x;
  for (int it = 0; it < 32; ++it) {
    int idx = it * 256 + tid;
    int k = idx >> 7, n = idx & 127;
    Tl[n][k] = f2b(Wo[(size_t)(k0 + k) * 2048 + n0 + n]);
  }
  __syncthreads();
  for (int it = 0; it < 32; ++it) {
    int idx = it * 256 + tid;
    int d = idx >> 6, kk = idx & 63;
    Wot[(size_t)(n0 + d) * 2048 + k0 + kk] = Tl[d][kk];
  }
}

// vb [B,H,T,128] bf16 -> vt [B,H,128,T] bf16 with sigma-permuted columns within
// each 64-tile: sigma(t) = (t&15)*4 + (t>>4). Matches attn's packed-P k-space.
__global__ void transpose_v_kernel(const u16* __restrict__ vb, u16* __restrict__ vt) {
  __shared__ u16 Tl[128 * 65];
  const int bh = blockIdx.y;
  const int t0 = blockIdx.x * 64;
  const int tid = threadIdx.x;
  const u16* src = vb + (size_t)bh * 2048 * 128;
  u16* dstp = vt + (size_t)bh * 128 * 2048;
#pragma unroll
  for (int c = 0; c < 4; ++c) {
    int ci = c * 256 + tid;
    int tr = ci >> 4, d0 = (ci & 15) * 8;
    u16x8 v = *(const u16x8*)(src + (size_t)(t0 + tr) * 128 + d0);
#pragma unroll
    for (int e = 0; e < 8; ++e) Tl[(d0 + e) * 65 + tr] = v[e];
  }
  __syncthreads();
#pragma unroll
  for (int it = 0; it < 32; ++it) {
    int idx = it * 256 + tid;
    int d = idx >> 6, tt = idx & 63;
    dstp[(size_t)d * 2048 + t0 + ((tt & 15) * 4 + (tt >> 4))] = Tl[d * 65 + tt];
  }
}

// ---------------- GEMM (128x128 tile, BK=32, 4 waves, m97 structure) ----------------
// 1D grid with XCD-chunked swizzle (nwg % 8 == 0). EPI 0: QKV epilogue
// (scatter + bias, Q pre-scaled by 1/sqrt(128)*log2e). EPI 1: f32 out + bo.
template <int EPI>
__global__ __launch_bounds__(256) void gemm_kernel(
    const u16* __restrict__ A, const u16* __restrict__ B,
    u16* __restrict__ qo, u16* __restrict__ ko, u16* __restrict__ vo,
    const float* __restrict__ bq, const float* __restrict__ bk, const float* __restrict__ bv,
    float* __restrict__ outf, const float* __restrict__ bo) {
  __shared__ u16 As[128 * 32];
  __shared__ u16 Bs[128 * 32];
  constexpr int NX = (EPI == 0) ? 48 : 16;
  const int nwg = gridDim.x;
  const int q8 = nwg >> 3;
  const int bid0 = blockIdx.x;
  const int gid = (bid0 & 7) * q8 + (bid0 >> 3);   // XCD-chunked, bijective
  const int m0 = (gid / NX) * 128, n0 = (gid % NX) * 128;

  const int tid = threadIdx.x;
  const int lane = tid & 63, wv = tid >> 6;
  const int wm = (wv >> 1) * 64, wn = (wv & 1) * 64;
  const int lr = lane & 15, lk = (lane >> 4) * 8;

  f32x4 zero = {0.f, 0.f, 0.f, 0.f};
  f32x4 acc[4][4];
#pragma unroll
  for (int i = 0; i < 4; ++i)
#pragma unroll
    for (int j = 0; j < 4; ++j) acc[i][j] = zero;

  const int e0 = tid * 8;
  const int row0 = e0 >> 5;
  const int col0 = e0 & 31;
  const u16* Ag = A + (size_t)(m0 + row0) * 2048 + col0;
  const u16* Bg = B + (size_t)(n0 + row0) * 2048 + col0;

  for (int kt = 0; kt < 2048; kt += 32) {
    gl_lds16(Ag + kt, As + e0);
    gl_lds16(Ag + kt + (size_t)64 * 2048, As + e0 + 64 * 32);
    gl_lds16(Bg + kt, Bs + e0);
    gl_lds16(Bg + kt + (size_t)64 * 2048, Bs + e0 + 64 * 32);
    __syncthreads();
    bf16x8 af[4], bfm[4];
#pragma unroll
    for (int i = 0; i < 4; ++i) af[i] = *(const bf16x8*)(As + (wm + i * 16 + lr) * 32 + lk);
#pragma unroll
    for (int j = 0; j < 4; ++j) bfm[j] = *(const bf16x8*)(Bs + (wn + j * 16 + lr) * 32 + lk);
#pragma unroll
    for (int i = 0; i < 4; ++i)
#pragma unroll
      for (int j = 0; j < 4; ++j)
        acc[i][j] = __builtin_amdgcn_mfma_f32_16x16x32_bf16(af[i], bfm[j], acc[i][j], 0, 0, 0);
    __syncthreads();
  }

  const int rbase = (lane >> 4) * 4;
  if (EPI == 0) {
    const int qkv = n0 >> 11, h = (n0 >> 7) & 15;
    const float* bias = (qkv == 0) ? bq : (qkv == 1) ? bk : bv;
    u16* dst = (qkv == 0) ? qo : (qkv == 1) ? ko : vo;
    const float qscale = 0.08838834764831845f * 1.4426950408889634f;  // 1/sqrt(128)*log2e
#pragma unroll
    for (int i = 0; i < 4; ++i)
#pragma unroll
      for (int j = 0; j < 4; ++j)
#pragma unroll
        for (int r = 0; r < 4; ++r) {
          int gm = m0 + wm + i * 16 + rbase + r;
          int d = wn + j * 16 + (lane & 15);
          float val = acc[i][j][r] + bias[h * 128 + d];
          if (qkv == 0) val *= qscale;
          int b = gm >> 11, t = gm & 2047;
          dst[((size_t)(b * 16 + h) * 2048 + t) * 128 + d] = f2b(val);
        }
  } else {
#pragma unroll
    for (int i = 0; i < 4; ++i)
#pragma unroll
      for (int j = 0; j < 4; ++j)
#pragma unroll
        for (int r = 0; r < 4; ++r) {
          int gm = m0 + wm + i * 16 + rbase + r;
          int gn = n0 + wn + j * 16 + (lane & 15);
          outf[(size_t)gm * 2048 + gn] = acc[i][j][r] + bo[gn];
        }
  }
}

// ---------------- flash attention (causal) ----------------
// 512 blocks of 256 threads; bid -> bh = bid&31 (XCD-grouped), qt = 15-(bid>>5)
// (heaviest blocks dispatch first; 2 blocks/CU co-resident at 80KB LDS).
// 4 waves x 32 q-rows; KV tile 64, double-buffered, gl_lds staging pre-swizzled.
// Softmax: per-lane partial row-sums (reduced once at end), defer-max with
// lane-local check (no per-tile shuffles on common path), packed b64 P stores
// in sigma-permuted k-space matching the sigma-permuted V^T.
// Q arrives pre-scaled by 1/sqrt(128)*log2e -> scores in exp2 domain.
__global__ __launch_bounds__(256) void attn_kernel(
    const u16* __restrict__ qg, const u16* __restrict__ kg,
    const u16* __restrict__ vtg, u16* __restrict__ y) {
  __shared__ u16 Kb[2][64 * 128];
  __shared__ u16 Vb[2][128 * 64];
  __shared__ u16 Pl[4][32 * 64];
  const int tid = threadIdx.x, lane = tid & 63, w = tid >> 6;
  const int bid = blockIdx.x;
  const int bh = bid & 31, qt = 15 - (bid >> 5);
  const int b = bh >> 4, h = bh & 15;
  const int lr = lane & 15, lk = (lane >> 4) * 8;
  const u16* Qp = qg + (size_t)bh * (2048 * 128);
  const u16* Kp = kg + (size_t)bh * (2048 * 128);
  const u16* Vp = vtg + (size_t)bh * (128 * 2048);

  int koff[4], voff[4], dstc[4];
#pragma unroll
  for (int c = 0; c < 4; ++c) {
    int ci = c * 256 + tid;
    dstc[c] = ci * 8;
    int kr = ci >> 4, kj = ci & 15;                 // K tile: 64 rows x 16 chunks
    koff[c] = kr * 128 + (kj ^ (kr & 7)) * 8;
    int vd = ci >> 3, vj = ci & 7;                  // V^T tile: 128 rows x 8 chunks
    voff[c] = vd * 2048 + (vj ^ (vd & 7)) * 8;
  }
  const int kxor = (lr & 7) << 4;
  const int rbase = (lane >> 4) * 4;
  const f32x4 zero = {0.f, 0.f, 0.f, 0.f};

  const int q0 = qt * 128;
  const int qw = q0 + w * 32;
  const int nt = 2 * qt + 2;

  bf16x8 qf[2][4];
#pragma unroll
  for (int s = 0; s < 2; ++s)
#pragma unroll
    for (int i = 0; i < 4; ++i)
      qf[s][i] = *(const bf16x8*)(Qp + (size_t)(qw + s * 16 + lr) * 128 + i * 32 + lk);

  f32x4 o[2][8];
#pragma unroll
  for (int s = 0; s < 2; ++s)
#pragma unroll
    for (int f = 0; f < 8; ++f) o[s][f] = zero;
  float mrow[2][4], lrow[2][4];
#pragma unroll
  for (int s = 0; s < 2; ++s)
#pragma unroll
    for (int r = 0; r < 4; ++r) { mrow[s][r] = -1e30f; lrow[s][r] = 0.f; }

  // prologue: stage tile 0
#pragma unroll
  for (int c = 0; c < 4; ++c) gl_lds16(Kp + koff[c], Kb[0] + dstc[c]);
#pragma unroll
  for (int c = 0; c < 4; ++c) gl_lds16(Vp + voff[c], Vb[0] + dstc[c]);
  __syncthreads();

  int cur = 0;
  for (int t = 0; t < nt; ++t) {
    const int s0 = t * 64;
    if (t + 1 < nt) {
      const size_t skn = (size_t)(s0 + 64) * 128;
#pragma unroll
      for (int c = 0; c < 4; ++c) gl_lds16(Kp + skn + koff[c], Kb[cur ^ 1] + dstc[c]);
#pragma unroll
      for (int c = 0; c < 4; ++c) gl_lds16(Vp + (s0 + 64) + voff[c], Vb[cur ^ 1] + dstc[c]);
    }
    if (s0 <= qw + 31) {
      const char* Kc = (const char*)Kb[cur];
      f32x4 sf[2][4];
      __builtin_amdgcn_s_setprio(1);
#pragma unroll
      for (int sj = 0; sj < 4; ++sj) {
        f32x4 a0 = zero, a1 = zero;
#pragma unroll
        for (int i = 0; i < 4; ++i) {
          bf16x8 kf = *(const bf16x8*)(Kc + ((((sj * 16 + lr) * 256) + (i * 32 + lk) * 2) ^ kxor));
          a0 = __builtin_amdgcn_mfma_f32_16x16x32_bf16(qf[0][i], kf, a0, 0, 0, 0);
          a1 = __builtin_amdgcn_mfma_f32_16x16x32_bf16(qf[1][i], kf, a1, 0, 0, 0);
        }
        sf[0][sj] = a0; sf[1][sj] = a1;
      }
      __builtin_amdgcn_s_setprio(0);

      char* Pc = (char*)Pl[w];
      const bool diag = (s0 + 63 > qw);             // wave-uniform: diagonal tile
      float pmax[2][4];
      bool need = false;
#pragma unroll
      for (int s = 0; s < 2; ++s)
#pragma unroll
        for (int r = 0; r < 4; ++r) {
          if (diag) {
            const int rq = qw + s * 16 + rbase + r;
#pragma unroll
            for (int sj = 0; sj < 4; ++sj)
              if (s0 + sj * 16 + lr > rq) sf[s][sj][r] = -1e30f;
          }
          float pm = fmaxf(fmaxf(sf[s][0][r], sf[s][1][r]),
                           fmaxf(sf[s][2][r], sf[s][3][r]));
          pmax[s][r] = pm;
          need |= (pm > mrow[s][r] + 8.f);
        }
      if (__any(need)) {                            // rare: full reduce + rescale
#pragma unroll
        for (int s = 0; s < 2; ++s)
#pragma unroll
          for (int r = 0; r < 4; ++r) {
            float pm = pmax[s][r];
            pm = fmaxf(pm, __shfl_xor(pm, 1));
            pm = fmaxf(pm, __shfl_xor(pm, 2));
            pm = fmaxf(pm, __shfl_xor(pm, 4));
            pm = fmaxf(pm, __shfl_xor(pm, 8));
            float mnew = fmaxf(mrow[s][r], pm);
            float sfac = __builtin_amdgcn_exp2f(mrow[s][r] - mnew);
            mrow[s][r] = mnew;
            lrow[s][r] *= sfac;
#pragma unroll
            for (int f = 0; f < 8; ++f) o[s][f][r] *= sfac;
          }
      }
      // P = exp2(S - m), per-lane partial sums, packed b64 store (sigma k-space)
#pragma unroll
      for (int s = 0; s < 2; ++s)
#pragma unroll
        for (int r = 0; r < 4; ++r) {
          const int prow = s * 16 + rbase + r;
          u16x4 pk;
          float ps = 0.f;
#pragma unroll
          for (int sj = 0; sj < 4; ++sj) {
            float p = __builtin_amdgcn_exp2f(sf[s][sj][r] - mrow[s][r]);
            ps += p;
            pk[sj] = f2b(p);
          }
          lrow[s][r] += ps;
          *(u16x4*)(Pc + ((prow * 128 + lr * 8) ^ ((prow & 7) << 4))) = pk;
        }

      const char* Vc = (const char*)Vb[cur];
      __builtin_amdgcn_s_setprio(1);
#pragma unroll
      for (int st = 0; st < 2; ++st) {
        bf16x8 pf0 = *(const bf16x8*)(Pc + (((lr * 128) + (st * 32 + lk) * 2) ^ kxor));
        bf16x8 pf1 = *(const bf16x8*)(Pc + ((((16 + lr) * 128) + (st * 32 + lk) * 2) ^ kxor));
#pragma unroll
        for (int f = 0; f < 8; ++f) {
          bf16x8 vf = *(const bf16x8*)(Vc + ((((f * 16 + lr) * 128) + (st * 32 + lk) * 2) ^ kxor));
          o[0][f] = __builtin_amdgcn_mfma_f32_16x16x32_bf16(pf0, vf, o[0][f], 0, 0, 0);
          o[1][f] = __builtin_amdgcn_mfma_f32_16x16x32_bf16(pf1, vf, o[1][f], 0, 0, 0);
        }
      }
      __builtin_amdgcn_s_setprio(0);
    }
    __syncthreads();
    cur ^= 1;
  }

  // epilogue: reduce per-lane row-sum partials once, then write
#pragma unroll
  for (int s = 0; s < 2; ++s)
#pragma unroll
    for (int r = 0; r < 4; ++r) {
      float l = lrow[s][r];
      l += __shfl_xor(l, 1);
      l += __shfl_xor(l, 2);
      l += __shfl_xor(l, 4);
      l += __shfl_xor(l, 8);
      const float rinv = __builtin_amdgcn_rcpf(l);
      const int row = qw + s * 16 + rbase + r;
#pragma unroll
      for (int f = 0; f < 8; ++f)
        y[((size_t)b * 2048 + row) * 2048 + h * 128 + f * 16 + lr] =
            f2b(o[s][f][r] * rinv);
    }
}

// ---------------- launch ----------------

extern "C" void kernel_launch(void* const* d_in, const int* in_sizes, int n_in,
                              void* d_out, int out_size, void* d_ws, size_t ws_size,
                              hipStream_t stream) {
  const float* x  = (const float*)d_in[0];
  const float* Wq = (const float*)d_in[1];
  const float* bq = (const float*)d_in[2];
  const float* Wk = (const float*)d_in[3];
  const float* bk = (const float*)d_in[4];
  const float* Wv = (const float*)d_in[5];
  const float* bv = (const float*)d_in[6];
  const float* Wo = (const float*)d_in[7];
  const float* bo = (const float*)d_in[8];
  float* out = (float*)d_out;
  char* ws = (char*)d_ws;

  u16* xb  = (u16*)(ws + 0);          // 16 MB; reused as yb after QKV GEMM
  u16* Wt  = (u16*)(ws + 16777216);   // 24 MB; front 8 MB reused as Wot, next 16 MB as vtb
  u16* qb  = (u16*)(ws + 41943040);   // 16 MB
  u16* kb  = (u16*)(ws + 58720256);   // 16 MB
  u16* vb  = (u16*)(ws + 75497472);   // 16 MB (total 88 MB)
  u16* Wot = Wt;                      // [2048][2048] bf16 = 8 MB
  u16* vtb = (u16*)(ws + 25165824);   // [B,H,128,T] bf16 = 16 MB
  u16* yb  = xb;

  cast_x_kernel<<<8192, 256, 0, stream>>>(x, xb, M_TOT * D_MODEL);
  trans_wqkv_kernel<<<dim3(32, 48), 256, 0, stream>>>(Wq, Wk, Wv, Wt);
  gemm_kernel<0><<<N_QKV / 128 * (M_TOT / 128), 256, 0, stream>>>(
      xb, Wt, qb, kb, vb, bq, bk, bv, nullptr, nullptr);
  trans_wo_kernel<<<dim3(32, 16), 256, 0, stream>>>(Wo, Wot);
  transpose_v_kernel<<<dim3(32, 32), 256, 0, stream>>>(vb, vtb);
  attn_kernel<<<512, 256, 0, stream>>>(qb, kb, vtb, yb);
  gemm_kernel<1><<<D_MODEL / 128 * (M_TOT / 128), 256, 0, stream>>>(
      yb, Wot, nullptr, nullptr, nullptr, nullptr, nullptr, nullptr, out, bo);
}

// Round 5
// 287.803 us; speedup vs baseline: 2.3570x; 1.0650x over previous
//
#include <hip/hip_runtime.h>
#include <stdint.h>

typedef unsigned short u16;
typedef __attribute__((ext_vector_type(4))) u16 u16x4;
typedef __attribute__((ext_vector_type(8))) u16 u16x8;
typedef __attribute__((ext_vector_type(8))) __bf16 bf16x8;
typedef __attribute__((ext_vector_type(4))) float f32x4;

#define D_MODEL 2048
#define N_HEADS 16
#define HEAD_DIM 128
#define BATCH 2
#define SEQ 2048
#define M_TOT (BATCH*SEQ)          // 4096
#define N_QKV (3*D_MODEL)          // 6144

__device__ __forceinline__ u16 f2b(float f) {
  union { float f; uint32_t u; } c; c.f = f;
  uint32_t u = c.u;
  uint32_t r = (u + 0x7fffu + ((u >> 16) & 1u)) >> 16;
  return (u16)r;
}

__device__ __forceinline__ void gl_lds16(const u16* g, u16* l) {
  __builtin_amdgcn_global_load_lds(
      (const __attribute__((address_space(1))) uint32_t*)g,
      (__attribute__((address_space(3))) uint32_t*)l, 16, 0, 0);
}

// ---------------- prep kernels ----------------

__global__ void cast_x_kernel(const float* __restrict__ x, u16* __restrict__ xb, int n) {
  int i = (blockIdx.x * blockDim.x + threadIdx.x) * 4;
  if (i >= n) return;
  f32x4 v = *(const f32x4*)(x + i);
  u16x4 o;
  o[0] = f2b(v[0]); o[1] = f2b(v[1]); o[2] = f2b(v[2]); o[3] = f2b(v[3]);
  *(u16x4*)(xb + i) = o;
}

// Wq/Wk/Wv [H][2048][128] f32  ->  Wt [6144][2048] bf16, row n=(qkv*2048+h*128+d), K-major
__global__ void trans_wqkv_kernel(const float* __restrict__ Wq, const float* __restrict__ Wk,
                                  const float* __restrict__ Wv, u16* __restrict__ Wt) {
  __shared__ u16 Tl[128][72];
  const int hh = blockIdx.y;           // 0..47 = qkv*16+h
  const int qkv = hh >> 4, h = hh & 15;
  const float* src = (qkv == 0 ? Wq : qkv == 1 ? Wk : Wv) + (size_t)h * 2048 * 128;
  const int k0 = blockIdx.x * 64;
  const int tid = threadIdx.x;
  for (int it = 0; it < 32; ++it) {
    int idx = it * 256 + tid;
    int k = idx >> 7, d = idx & 127;
    Tl[d][k] = f2b(src[(size_t)(k0 + k) * 128 + d]);
  }
  __syncthreads();
  for (int it = 0; it < 32; ++it) {
    int idx = it * 256 + tid;
    int d = idx >> 6, kk = idx & 63;
    Wt[(size_t)(hh * 128 + d) * 2048 + k0 + kk] = Tl[d][kk];
  }
}

// Wo [2048][2048] f32 -> Wot [2048][2048] bf16 (transposed, K-major)
__global__ void trans_wo_kernel(const float* __restrict__ Wo, u16* __restrict__ Wot) {
  __shared__ u16 Tl[128][72];
  const int k0 = blockIdx.x * 64;     // 32 tiles
  const int n0 = blockIdx.y * 128;    // 16 tiles
  const int tid = threadIdx.x;
  for (int it = 0; it < 32; ++it) {
    int idx = it * 256 + tid;
    int k = idx >> 7, n = idx & 127;
    Tl[n][k] = f2b(Wo[(size_t)(k0 + k) * 2048 + n0 + n]);
  }
  __syncthreads();
  for (int it = 0; it < 32; ++it) {
    int idx = it * 256 + tid;
    int d = idx >> 6, kk = idx & 63;
    Wot[(size_t)(n0 + d) * 2048 + k0 + kk] = Tl[d][kk];
  }
}

// vb [B,H,T,128] bf16 -> vt [B,H,128,T] bf16 with sigma-permuted columns within
// each 64-tile: sigma(t) = (t&15)*4 + (t>>4). Matches attn's packed-P k-space.
__global__ void transpose_v_kernel(const u16* __restrict__ vb, u16* __restrict__ vt) {
  __shared__ u16 Tl[128 * 65];
  const int bh = blockIdx.y;
  const int t0 = blockIdx.x * 64;
  const int tid = threadIdx.x;
  const u16* src = vb + (size_t)bh * 2048 * 128;
  u16* dstp = vt + (size_t)bh * 128 * 2048;
#pragma unroll
  for (int c = 0; c < 4; ++c) {
    int ci = c * 256 + tid;
    int tr = ci >> 4, d0 = (ci & 15) * 8;
    u16x8 v = *(const u16x8*)(src + (size_t)(t0 + tr) * 128 + d0);
#pragma unroll
    for (int e = 0; e < 8; ++e) Tl[(d0 + e) * 65 + tr] = v[e];
  }
  __syncthreads();
#pragma unroll
  for (int it = 0; it < 32; ++it) {
    int idx = it * 256 + tid;
    int d = idx >> 6, tt = idx & 63;
    dstp[(size_t)d * 2048 + t0 + ((tt & 15) * 4 + (tt >> 4))] = Tl[d * 65 + tt];
  }
}

// ---------------- GEMM: 256x128 tile, BK=64, ring-3 LDS, counted vmcnt ----------------
// 512 threads = 8 waves (2M x 4N), per-wave 128x32 output (8i x 2j fragments).
// LDS: A ring[3][256][64], B ring[3][128][64] bf16, XOR-swizzled (byte ^= (row&7)<<4),
// staged via global_load_lds with pre-swizzled global source (linear LDS dest).
// Per K-tile: 2 phases of {ds_reads | 3 staging loads for kt+2 | 16 MFMA | s_barrier};
// s_waitcnt vmcnt(6) once per K-tile (stage-to-use distance = 2 K-tiles), drain only
// at the last boundary. EPI 0: QKV scatter + bias (Q pre-scaled). EPI 1: f32 + bo.
template <int EPI>
__global__ __launch_bounds__(512, 2) void gemm256_kernel(
    const u16* __restrict__ A, const u16* __restrict__ B,
    u16* __restrict__ qo, u16* __restrict__ ko, u16* __restrict__ vo,
    const float* __restrict__ bq, const float* __restrict__ bk, const float* __restrict__ bv,
    float* __restrict__ outf, const float* __restrict__ bo) {
  __shared__ u16 As[3][256 * 64];   // 96 KB
  __shared__ u16 Bs[3][128 * 64];   // 48 KB
  constexpr int NX = (EPI == 0) ? 48 : 16;
  const int nwg = gridDim.x, q8 = nwg >> 3, bid0 = blockIdx.x;
  const int gid = (bid0 & 7) * q8 + (bid0 >> 3);   // XCD-chunked, bijective
  const int m0 = (gid / NX) * 256, n0 = (gid % NX) * 128;

  const int tid = threadIdx.x;
  const int lane = tid & 63, w = tid >> 6;
  const int wm = (w >> 2) * 128, wn = (w & 3) * 32;
  const int lr = lane & 15, lk = (lane >> 4) * 8;

  // staging: LDS linear chunk (row, j) holds global chunk (row, j^(row&7))
  int aoff[4], adst[4], boff[2], bdst[2];
#pragma unroll
  for (int l = 0; l < 4; ++l) {
    int ci = l * 512 + tid, row = ci >> 3, j = ci & 7;
    aoff[l] = (m0 + row) * 2048 + (j ^ (row & 7)) * 8;
    adst[l] = ci * 8;
  }
#pragma unroll
  for (int l = 0; l < 2; ++l) {
    int ci = l * 512 + tid, row = ci >> 3, j = ci & 7;
    boff[l] = (n0 + row) * 2048 + (j ^ (row & 7)) * 8;
    bdst[l] = ci * 8;
  }

  f32x4 acc[8][2];
  const f32x4 zero = {0.f, 0.f, 0.f, 0.f};
#pragma unroll
  for (int i = 0; i < 8; ++i) { acc[i][0] = zero; acc[i][1] = zero; }

  // prologue: stage kt=0 -> slot 0, kt=1 -> slot 1 (12 loads/thread)
#pragma unroll
  for (int s = 0; s < 2; ++s) {
#pragma unroll
    for (int l = 0; l < 4; ++l) gl_lds16(A + aoff[l] + s * 64, As[s] + adst[l]);
#pragma unroll
    for (int l = 0; l < 2; ++l) gl_lds16(B + boff[l] + s * 64, Bs[s] + bdst[l]);
  }
  asm volatile("s_waitcnt vmcnt(6)" ::: "memory");   // kt=0 landed, kt=1 in flight
  __builtin_amdgcn_s_barrier();

  int slot = 0;
  for (int kt = 0; kt < 32; ++kt) {
    const char* Ac = (const char*)As[slot];
    const char* Bc = (const char*)Bs[slot];
    const int s2 = (slot + 2 >= 3) ? slot - 1 : slot + 2;  // staging slot (kt+2)
    const bool st = (kt < 30);
    const int k2 = (kt + 2) * 64;

    bf16x8 af[4][2], bfr[2][2];
    // ---- phase 0: fragments i0-3 + B, stage part 1 of kt+2 ----
#pragma unroll
    for (int i = 0; i < 4; ++i) {
      const int row = wm + i * 16 + lr;
      const int rb = row * 128, rx = (row & 7) << 4;
#pragma unroll
      for (int kk = 0; kk < 2; ++kk)
        af[i][kk] = *(const bf16x8*)(Ac + ((rb + (kk * 32 + lk) * 2) ^ rx));
    }
#pragma unroll
    for (int j = 0; j < 2; ++j) {
      const int row = wn + j * 16 + lr;
      const int rb = row * 128, rx = (row & 7) << 4;
#pragma unroll
      for (int kk = 0; kk < 2; ++kk)
        bfr[j][kk] = *(const bf16x8*)(Bc + ((rb + (kk * 32 + lk) * 2) ^ rx));
    }
    if (st) {
      gl_lds16(A + aoff[0] + k2, As[s2] + adst[0]);
      gl_lds16(A + aoff[1] + k2, As[s2] + adst[1]);
      gl_lds16(B + boff[0] + k2, Bs[s2] + bdst[0]);
    }
    __builtin_amdgcn_s_setprio(1);
#pragma unroll
    for (int i = 0; i < 4; ++i)
#pragma unroll
      for (int j = 0; j < 2; ++j)
#pragma unroll
        for (int kk = 0; kk < 2; ++kk)
          acc[i][j] = __builtin_amdgcn_mfma_f32_16x16x32_bf16(af[i][kk], bfr[j][kk], acc[i][j], 0, 0, 0);
    __builtin_amdgcn_s_setprio(0);
    __builtin_amdgcn_s_barrier();

    // ---- phase 1: fragments i4-7, stage part 2 of kt+2 ----
#pragma unroll
    for (int i = 0; i < 4; ++i) {
      const int row = wm + 64 + i * 16 + lr;
      const int rb = row * 128, rx = (row & 7) << 4;
#pragma unroll
      for (int kk = 0; kk < 2; ++kk)
        af[i][kk] = *(const bf16x8*)(Ac + ((rb + (kk * 32 + lk) * 2) ^ rx));
    }
    if (st) {
      gl_lds16(A + aoff[2] + k2, As[s2] + adst[2]);
      gl_lds16(A + aoff[3] + k2, As[s2] + adst[3]);
      gl_lds16(B + boff[1] + k2, Bs[s2] + bdst[1]);
    }
    __builtin_amdgcn_s_setprio(1);
#pragma unroll
    for (int i = 0; i < 4; ++i)
#pragma unroll
      for (int j = 0; j < 2; ++j)
#pragma unroll
        for (int kk = 0; kk < 2; ++kk)
          acc[i + 4][j] = __builtin_amdgcn_mfma_f32_16x16x32_bf16(af[i][kk], bfr[j][kk], acc[i + 4][j], 0, 0, 0);
    __builtin_amdgcn_s_setprio(0);
    if (kt == 30)      asm volatile("s_waitcnt vmcnt(0)" ::: "memory");
    else if (kt < 30)  asm volatile("s_waitcnt vmcnt(6)" ::: "memory");
    __builtin_amdgcn_s_barrier();
    slot = (slot + 1 >= 3) ? 0 : slot + 1;
  }

  const int rbase = (lane >> 4) * 4;
  if (EPI == 0) {
    const int qkv = n0 >> 11, h = (n0 >> 7) & 15;
    const float* bias = (qkv == 0) ? bq : (qkv == 1) ? bk : bv;
    u16* dst = (qkv == 0) ? qo : (qkv == 1) ? ko : vo;
    const float qscale = 0.08838834764831845f * 1.4426950408889634f;  // 1/sqrt(128)*log2e
#pragma unroll
    for (int i = 0; i < 8; ++i)
#pragma unroll
      for (int j = 0; j < 2; ++j)
#pragma unroll
        for (int r = 0; r < 4; ++r) {
          int gm = m0 + wm + i * 16 + rbase + r;
          int d = wn + j * 16 + lr;
          float val = acc[i][j][r] + bias[h * 128 + d];
          if (qkv == 0) val *= qscale;
          int b = gm >> 11, t = gm & 2047;
          dst[((size_t)(b * 16 + h) * 2048 + t) * 128 + d] = f2b(val);
        }
  } else {
#pragma unroll
    for (int i = 0; i < 8; ++i)
#pragma unroll
      for (int j = 0; j < 2; ++j)
#pragma unroll
        for (int r = 0; r < 4; ++r) {
          int gm = m0 + wm + i * 16 + rbase + r;
          int gn = n0 + wn + j * 16 + lr;
          outf[(size_t)gm * 2048 + gn] = acc[i][j][r] + bo[gn];
        }
  }
}

// ---------------- flash attention (causal) ----------------
// 512 blocks of 256 threads; bid -> bh = bid&31 (XCD-grouped), qt = 15-(bid>>5)
// (heaviest blocks dispatch first; 2 blocks/CU co-resident at 80KB LDS).
// 4 waves x 32 q-rows; KV tile 64, double-buffered, gl_lds staging pre-swizzled.
// Softmax: per-lane partial row-sums (reduced once at end), defer-max with
// lane-local check (no per-tile shuffles on common path), packed b64 P stores
// in sigma-permuted k-space matching the sigma-permuted V^T.
// Q arrives pre-scaled by 1/sqrt(128)*log2e -> scores in exp2 domain.
__global__ __launch_bounds__(256) void attn_kernel(
    const u16* __restrict__ qg, const u16* __restrict__ kg,
    const u16* __restrict__ vtg, u16* __restrict__ y) {
  __shared__ u16 Kb[2][64 * 128];
  __shared__ u16 Vb[2][128 * 64];
  __shared__ u16 Pl[4][32 * 64];
  const int tid = threadIdx.x, lane = tid & 63, w = tid >> 6;
  const int bid = blockIdx.x;
  const int bh = bid & 31, qt = 15 - (bid >> 5);
  const int b = bh >> 4, h = bh & 15;
  const int lr = lane & 15, lk = (lane >> 4) * 8;
  const u16* Qp = qg + (size_t)bh * (2048 * 128);
  const u16* Kp = kg + (size_t)bh * (2048 * 128);
  const u16* Vp = vtg + (size_t)bh * (128 * 2048);

  int koff[4], voff[4], dstc[4];
#pragma unroll
  for (int c = 0; c < 4; ++c) {
    int ci = c * 256 + tid;
    dstc[c] = ci * 8;
    int kr = ci >> 4, kj = ci & 15;                 // K tile: 64 rows x 16 chunks
    koff[c] = kr * 128 + (kj ^ (kr & 7)) * 8;
    int vd = ci >> 3, vj = ci & 7;                  // V^T tile: 128 rows x 8 chunks
    voff[c] = vd * 2048 + (vj ^ (vd & 7)) * 8;
  }
  const int kxor = (lr & 7) << 4;
  const int rbase = (lane >> 4) * 4;
  const f32x4 zero = {0.f, 0.f, 0.f, 0.f};

  const int q0 = qt * 128;
  const int qw = q0 + w * 32;
  const int nt = 2 * qt + 2;

  bf16x8 qf[2][4];
#pragma unroll
  for (int s = 0; s < 2; ++s)
#pragma unroll
    for (int i = 0; i < 4; ++i)
      qf[s][i] = *(const bf16x8*)(Qp + (size_t)(qw + s * 16 + lr) * 128 + i * 32 + lk);

  f32x4 o[2][8];
#pragma unroll
  for (int s = 0; s < 2; ++s)
#pragma unroll
    for (int f = 0; f < 8; ++f) o[s][f] = zero;
  float mrow[2][4], lrow[2][4];
#pragma unroll
  for (int s = 0; s < 2; ++s)
#pragma unroll
    for (int r = 0; r < 4; ++r) { mrow[s][r] = -1e30f; lrow[s][r] = 0.f; }

  // prologue: stage tile 0
#pragma unroll
  for (int c = 0; c < 4; ++c) gl_lds16(Kp + koff[c], Kb[0] + dstc[c]);
#pragma unroll
  for (int c = 0; c < 4; ++c) gl_lds16(Vp + voff[c], Vb[0] + dstc[c]);
  __syncthreads();

  int cur = 0;
  for (int t = 0; t < nt; ++t) {
    const int s0 = t * 64;
    if (t + 1 < nt) {
      const size_t skn = (size_t)(s0 + 64) * 128;
#pragma unroll
      for (int c = 0; c < 4; ++c) gl_lds16(Kp + skn + koff[c], Kb[cur ^ 1] + dstc[c]);
#pragma unroll
      for (int c = 0; c < 4; ++c) gl_lds16(Vp + (s0 + 64) + voff[c], Vb[cur ^ 1] + dstc[c]);
    }
    if (s0 <= qw + 31) {
      const char* Kc = (const char*)Kb[cur];
      f32x4 sf[2][4];
      __builtin_amdgcn_s_setprio(1);
#pragma unroll
      for (int sj = 0; sj < 4; ++sj) {
        f32x4 a0 = zero, a1 = zero;
#pragma unroll
        for (int i = 0; i < 4; ++i) {
          bf16x8 kf = *(const bf16x8*)(Kc + ((((sj * 16 + lr) * 256) + (i * 32 + lk) * 2) ^ kxor));
          a0 = __builtin_amdgcn_mfma_f32_16x16x32_bf16(qf[0][i], kf, a0, 0, 0, 0);
          a1 = __builtin_amdgcn_mfma_f32_16x16x32_bf16(qf[1][i], kf, a1, 0, 0, 0);
        }
        sf[0][sj] = a0; sf[1][sj] = a1;
      }
      __builtin_amdgcn_s_setprio(0);

      char* Pc = (char*)Pl[w];
      const bool diag = (s0 + 63 > qw);             // wave-uniform: diagonal tile
      float pmax[2][4];
      bool need = false;
#pragma unroll
      for (int s = 0; s < 2; ++s)
#pragma unroll
        for (int r = 0; r < 4; ++r) {
          if (diag) {
            const int rq = qw + s * 16 + rbase + r;
#pragma unroll
            for (int sj = 0; sj < 4; ++sj)
              if (s0 + sj * 16 + lr > rq) sf[s][sj][r] = -1e30f;
          }
          float pm = fmaxf(fmaxf(sf[s][0][r], sf[s][1][r]),
                           fmaxf(sf[s][2][r], sf[s][3][r]));
          pmax[s][r] = pm;
          need |= (pm > mrow[s][r] + 8.f);
        }
      if (__any(need)) {                            // rare: full reduce + rescale
#pragma unroll
        for (int s = 0; s < 2; ++s)
#pragma unroll
          for (int r = 0; r < 4; ++r) {
            float pm = pmax[s][r];
            pm = fmaxf(pm, __shfl_xor(pm, 1));
            pm = fmaxf(pm, __shfl_xor(pm, 2));
            pm = fmaxf(pm, __shfl_xor(pm, 4));
            pm = fmaxf(pm, __shfl_xor(pm, 8));
            float mnew = fmaxf(mrow[s][r], pm);
            float sfac = __builtin_amdgcn_exp2f(mrow[s][r] - mnew);
            mrow[s][r] = mnew;
            lrow[s][r] *= sfac;
#pragma unroll
            for (int f = 0; f < 8; ++f) o[s][f][r] *= sfac;
          }
      }
      // P = exp2(S - m), per-lane partial sums, packed b64 store (sigma k-space)
#pragma unroll
      for (int s = 0; s < 2; ++s)
#pragma unroll
        for (int r = 0; r < 4; ++r) {
          const int prow = s * 16 + rbase + r;
          u16x4 pk;
          float ps = 0.f;
#pragma unroll
          for (int sj = 0; sj < 4; ++sj) {
            float p = __builtin_amdgcn_exp2f(sf[s][sj][r] - mrow[s][r]);
            ps += p;
            pk[sj] = f2b(p);
          }
          lrow[s][r] += ps;
          *(u16x4*)(Pc + ((prow * 128 + lr * 8) ^ ((prow & 7) << 4))) = pk;
        }

      const char* Vc = (const char*)Vb[cur];
      __builtin_amdgcn_s_setprio(1);
#pragma unroll
      for (int st = 0; st < 2; ++st) {
        bf16x8 pf0 = *(const bf16x8*)(Pc + (((lr * 128) + (st * 32 + lk) * 2) ^ kxor));
        bf16x8 pf1 = *(const bf16x8*)(Pc + ((((16 + lr) * 128) + (st * 32 + lk) * 2) ^ kxor));
#pragma unroll
        for (int f = 0; f < 8; ++f) {
          bf16x8 vf = *(const bf16x8*)(Vc + ((((f * 16 + lr) * 128) + (st * 32 + lk) * 2) ^ kxor));
          o[0][f] = __builtin_amdgcn_mfma_f32_16x16x32_bf16(pf0, vf, o[0][f], 0, 0, 0);
          o[1][f] = __builtin_amdgcn_mfma_f32_16x16x32_bf16(pf1, vf, o[1][f], 0, 0, 0);
        }
      }
      __builtin_amdgcn_s_setprio(0);
    }
    __syncthreads();
    cur ^= 1;
  }

  // epilogue: reduce per-lane row-sum partials once, then write
#pragma unroll
  for (int s = 0; s < 2; ++s)
#pragma unroll
    for (int r = 0; r < 4; ++r) {
      float l = lrow[s][r];
      l += __shfl_xor(l, 1);
      l += __shfl_xor(l, 2);
      l += __shfl_xor(l, 4);
      l += __shfl_xor(l, 8);
      const float rinv = __builtin_amdgcn_rcpf(l);
      const int row = qw + s * 16 + rbase + r;
#pragma unroll
      for (int f = 0; f < 8; ++f)
        y[((size_t)b * 2048 + row) * 2048 + h * 128 + f * 16 + lr] =
            f2b(o[s][f][r] * rinv);
    }
}

// ---------------- launch ----------------

extern "C" void kernel_launch(void* const* d_in, const int* in_sizes, int n_in,
                              void* d_out, int out_size, void* d_ws, size_t ws_size,
                              hipStream_t stream) {
  const float* x  = (const float*)d_in[0];
  const float* Wq = (const float*)d_in[1];
  const float* bq = (const float*)d_in[2];
  const float* Wk = (const float*)d_in[3];
  const float* bk = (const float*)d_in[4];
  const float* Wv = (const float*)d_in[5];
  const float* bv = (const float*)d_in[6];
  const float* Wo = (const float*)d_in[7];
  const float* bo = (const float*)d_in[8];
  float* out = (float*)d_out;
  char* ws = (char*)d_ws;

  u16* xb  = (u16*)(ws + 0);          // 16 MB; reused as yb after QKV GEMM
  u16* Wt  = (u16*)(ws + 16777216);   // 24 MB; front 8 MB reused as Wot, next 16 MB as vtb
  u16* qb  = (u16*)(ws + 41943040);   // 16 MB
  u16* kb  = (u16*)(ws + 58720256);   // 16 MB
  u16* vb  = (u16*)(ws + 75497472);   // 16 MB (total 88 MB)
  u16* Wot = Wt;                      // [2048][2048] bf16 = 8 MB
  u16* vtb = (u16*)(ws + 25165824);   // [B,H,128,T] bf16 = 16 MB
  u16* yb  = xb;

  cast_x_kernel<<<8192, 256, 0, stream>>>(x, xb, M_TOT * D_MODEL);
  trans_wqkv_kernel<<<dim3(32, 48), 256, 0, stream>>>(Wq, Wk, Wv, Wt);
  gemm256_kernel<0><<<768, 512, 0, stream>>>(
      xb, Wt, qb, kb, vb, bq, bk, bv, nullptr, nullptr);
  trans_wo_kernel<<<dim3(32, 16), 256, 0, stream>>>(Wo, Wot);
  transpose_v_kernel<<<dim3(32, 32), 256, 0, stream>>>(vb, vtb);
  attn_kernel<<<512, 256, 0, stream>>>(qb, kb, vtb, yb);
  gemm256_kernel<1><<<256, 512, 0, stream>>>(
      yb, Wot, nullptr, nullptr, nullptr, nullptr, nullptr, nullptr, out, bo);
}